// Round 1
// baseline (850.512 us; speedup 1.0000x reference)
//
#include <hip/hip_runtime.h>
#include <math.h>

#define D 128

// ---------------- CSR build ----------------

__global__ void k_init_deg(int* deg, int N) {
    int i = blockIdx.x * blockDim.x + threadIdx.x;
    if (i < N) deg[i] = 1;   // self-loop pre-counted
}

__global__ void k_count(const int* __restrict__ dst, int E, int* deg) {
    int i = blockIdx.x * blockDim.x + threadIdx.x;
    if (i < E) atomicAdd(&deg[dst[i]], 1);
}

__global__ void k_scan1(const int* __restrict__ deg, int N, int* tmp, int* bsum) {
    __shared__ int sh[256];
    int t = threadIdx.x;
    int i = blockIdx.x * 256 + t;
    int v = (i < N) ? deg[i] : 0;
    sh[t] = v;
    __syncthreads();
    for (int o = 1; o < 256; o <<= 1) {
        int u = (t >= o) ? sh[t - o] : 0;
        __syncthreads();
        sh[t] += u;
        __syncthreads();
    }
    if (i < N) tmp[i] = sh[t] - v;          // exclusive
    if (t == 255) bsum[blockIdx.x] = sh[255];
}

__global__ void k_scan2(int* bsum, int B) {
    __shared__ int sh[256];
    int t = threadIdx.x;
    int v = (t < B) ? bsum[t] : 0;
    sh[t] = v;
    __syncthreads();
    for (int o = 1; o < 256; o <<= 1) {
        int u = (t >= o) ? sh[t - o] : 0;
        __syncthreads();
        sh[t] += u;
        __syncthreads();
    }
    bsum[t] = sh[t] - v;                    // exclusive scan of block sums
}

__global__ void k_scan3(const int* __restrict__ tmp, const int* __restrict__ bscan,
                        int N, int total, int* rowptr, int* fill) {
    int i = blockIdx.x * blockDim.x + threadIdx.x;
    if (i < N) {
        int r = tmp[i] + bscan[i >> 8];
        rowptr[i] = r;
        fill[i] = r;
    }
    if (i == 0) rowptr[N] = total;
}

__global__ void k_fill(const int* __restrict__ ei, int E, int N, int* fill, int* csr) {
    int i = blockIdx.x * blockDim.x + threadIdx.x;
    int total = E + N;
    if (i >= total) return;
    int s_, d_;
    if (i < E) { s_ = ei[i]; d_ = ei[E + i]; }
    else       { s_ = d_ = i - E; }         // self loop
    int p = atomicAdd(&fill[d_], 1);
    csr[p] = s_;
}

// ---------------- expmap0 ----------------

__global__ void k_expmap(const float* __restrict__ x, float* __restrict__ out, int N) {
    int lane = threadIdx.x & 63;
    int node = blockIdx.x * (blockDim.x >> 6) + (threadIdx.x >> 6);
    if (node >= N) return;
    float2 v = *(const float2*)&x[(size_t)node * D + 2 * lane];
    float ss = v.x * v.x + v.y * v.y;
    for (int o = 32; o; o >>= 1) ss += __shfl_xor(ss, o, 64);
    float n = sqrtf(ss);
    n = fmaxf(n, 1e-15f);
    float sc = tanhf(n) / n;
    float2 r;
    r.x = v.x * sc;
    r.y = v.y * sc;
    *(float2*)&out[(size_t)node * D + 2 * lane] = r;
}

// ---------------- fp32 GEMM: H[N,128] = A[N,128] @ W[128,128] ----------------
// block = 256 threads, 32 rows/block, 4x4 register tile/thread.
// LDS: W 64KB + A 16KB = 80KB -> 2 blocks/CU.

__global__ __launch_bounds__(256, 2) void k_gemm(const float* __restrict__ A,
                                                 const float* __restrict__ W,
                                                 float* __restrict__ H, int N) {
    __shared__ float Wsh[D * D];
    __shared__ float Ash[32 * D];
    int t = threadIdx.x;
    int row0 = blockIdx.x * 32;
    for (int k = 0; k < D * D; k += 256) Wsh[k + t] = W[k + t];
    for (int k = 0; k < 32 * D; k += 256) {
        int idx = k + t;
        int r = row0 + (idx >> 7);
        Ash[idx] = (r < N) ? A[(size_t)row0 * D + idx] : 0.f;
    }
    __syncthreads();
    int c0 = (t & 31) * 4;
    int r0 = (t >> 5) * 4;
    float acc[4][4] = {};
#pragma unroll 4
    for (int k = 0; k < D; k++) {
        float4 w = *(const float4*)&Wsh[k * D + c0];
        float a0 = Ash[(r0 + 0) * D + k];
        float a1 = Ash[(r0 + 1) * D + k];
        float a2 = Ash[(r0 + 2) * D + k];
        float a3 = Ash[(r0 + 3) * D + k];
        acc[0][0] += a0 * w.x; acc[0][1] += a0 * w.y; acc[0][2] += a0 * w.z; acc[0][3] += a0 * w.w;
        acc[1][0] += a1 * w.x; acc[1][1] += a1 * w.y; acc[1][2] += a1 * w.z; acc[1][3] += a1 * w.w;
        acc[2][0] += a2 * w.x; acc[2][1] += a2 * w.y; acc[2][2] += a2 * w.z; acc[2][3] += a2 * w.w;
        acc[3][0] += a3 * w.x; acc[3][1] += a3 * w.y; acc[3][2] += a3 * w.z; acc[3][3] += a3 * w.w;
    }
    for (int r = 0; r < 4; r++) {
        int gr = row0 + r0 + r;
        if (gr < N) {
            float4 o;
            o.x = acc[r][0]; o.y = acc[r][1]; o.z = acc[r][2]; o.w = acc[r][3];
            *(float4*)&H[(size_t)gr * D + c0] = o;
        }
    }
}

// ---------------- per-node attention dots s = h@a_src, d = h@a_dst ----------------

__global__ void k_sdots(const float* __restrict__ H, const float* __restrict__ aS,
                        const float* __restrict__ aD, float* __restrict__ sA,
                        float* __restrict__ dA, int N) {
    int lane = threadIdx.x & 63;
    int node = blockIdx.x * (blockDim.x >> 6) + (threadIdx.x >> 6);
    if (node >= N) return;
    float2 h2 = *(const float2*)&H[(size_t)node * D + 2 * lane];
    float2 a2 = *(const float2*)&aS[2 * lane];
    float2 b2 = *(const float2*)&aD[2 * lane];
    float vs = h2.x * a2.x + h2.y * a2.y;
    float vd = h2.x * b2.x + h2.y * b2.y;
    for (int o = 32; o; o >>= 1) {
        vs += __shfl_xor(vs, o, 64);
        vd += __shfl_xor(vd, o, 64);
    }
    if (lane == 0) { sA[node] = vs; dA[node] = vd; }
}

// ---------------- softmax + weighted aggregation, one wave per dst node ----------------

template <bool ACT>
__global__ void k_agg(const float* __restrict__ H, const float* __restrict__ sA,
                      const float* __restrict__ dA, const int* __restrict__ rowptr,
                      const int* __restrict__ csr, const float* __restrict__ bias,
                      float* __restrict__ out, int N) {
    int lane = threadIdx.x & 63;
    int node = blockIdx.x * (blockDim.x >> 6) + (threadIdx.x >> 6);
    if (node >= N) return;
    int start = rowptr[node];
    int end = rowptr[node + 1];
    float di = dA[node];

    // pass A: segment max
    float mx = -3.4e38f;
    for (int j0 = start; j0 < end; j0 += 64) {
        int j = j0 + lane;
        if (j < end) {
            float e = sA[csr[j]] + di;
            e = (e > 0.f) ? e : 0.2f * e;
            mx = fmaxf(mx, e);
        }
    }
    for (int o = 32; o; o >>= 1) mx = fmaxf(mx, __shfl_xor(mx, o, 64));

    // pass B: denominator
    float den = 0.f;
    for (int j0 = start; j0 < end; j0 += 64) {
        int j = j0 + lane;
        if (j < end) {
            float e = sA[csr[j]] + di;
            e = (e > 0.f) ? e : 0.2f * e;
            den += expf(e - mx);
        }
    }
    for (int o = 32; o; o >>= 1) den += __shfl_xor(den, o, 64);

    // pass C: weighted aggregation of h[src] rows
    float acc0 = 0.f, acc1 = 0.f;
    for (int j0 = start; j0 < end; j0 += 64) {
        int j = j0 + lane;
        int sj = 0;
        float w = 0.f;
        if (j < end) {
            sj = csr[j];
            float e = sA[sj] + di;
            e = (e > 0.f) ? e : 0.2f * e;
            w = expf(e - mx);
        }
        int cnt = min(64, end - j0);
        for (int tt = 0; tt < cnt; tt++) {
            float wt = __shfl(w, tt, 64);
            int sjt = __shfl(sj, tt, 64);
            float2 hv = *(const float2*)&H[(size_t)sjt * D + 2 * lane];
            acc0 += wt * hv.x;
            acc1 += wt * hv.y;
        }
    }
    float inv = 1.f / den;
    acc0 = acc0 * inv + bias[2 * lane];
    acc1 = acc1 * inv + bias[2 * lane + 1];
    if (ACT) {
        acc0 = 2.f * tanhf(acc0);
        acc1 = 2.f * tanhf(acc1);
    }
    *(float2*)&out[(size_t)node * D + 2 * lane] = make_float2(acc0, acc1);
}

// ---------------- launch ----------------

extern "C" void kernel_launch(void* const* d_in, const int* in_sizes, int n_in,
                              void* d_out, int out_size, void* d_ws, size_t ws_size,
                              hipStream_t stream) {
    const int N = in_sizes[0] / D;
    const int E = in_sizes[1] / 2;
    const float* x = (const float*)d_in[0];
    const int* ei = (const int*)d_in[1];
    const float* Wm[3] = {(const float*)d_in[2], (const float*)d_in[6], (const float*)d_in[10]};
    const float* aS[3] = {(const float*)d_in[3], (const float*)d_in[7], (const float*)d_in[11]};
    const float* aD[3] = {(const float*)d_in[4], (const float*)d_in[8], (const float*)d_in[12]};
    const float* bb[3] = {(const float*)d_in[5], (const float*)d_in[9], (const float*)d_in[13]};

    char* ws = (char*)d_ws;
    size_t off = 0;
    auto alloc = [&](size_t bytes) -> void* {
        void* p = ws + off;
        off = (off + bytes + 511) & ~(size_t)511;
        return p;
    };
    float* bufA = (float*)alloc((size_t)N * D * 4);
    float* bufB = (float*)alloc((size_t)N * D * 4);
    float* sArr = (float*)alloc((size_t)N * 4);
    float* dArr = (float*)alloc((size_t)N * 4);
    int* deg    = (int*)alloc((size_t)N * 4);       // reused as fill cursor
    int* rowptr = (int*)alloc((size_t)(N + 1) * 4);
    int* tmp    = (int*)alloc((size_t)N * 4);
    int* bsum   = (int*)alloc(256 * 4);
    int* csr    = (int*)alloc((size_t)(E + N) * 4);
    (void)ws_size; (void)n_in; (void)out_size;

    const int B1 = (N + 255) / 256;   // 196 for N=50000 (fits single-block scan2)

    k_init_deg<<<B1, 256, 0, stream>>>(deg, N);
    k_count<<<(E + 255) / 256, 256, 0, stream>>>(ei + E, E, deg);
    k_scan1<<<B1, 256, 0, stream>>>(deg, N, tmp, bsum);
    k_scan2<<<1, 256, 0, stream>>>(bsum, B1);
    k_scan3<<<B1, 256, 0, stream>>>(tmp, bsum, N, E + N, rowptr, deg);
    k_fill<<<(E + N + 255) / 256, 256, 0, stream>>>(ei, E, N, deg, csr);

    k_expmap<<<(N + 3) / 4, 256, 0, stream>>>(x, bufA, N);

    for (int l = 0; l < 3; l++) {
        k_gemm<<<(N + 31) / 32, 256, 0, stream>>>(bufA, Wm[l], bufB, N);
        k_sdots<<<(N + 3) / 4, 256, 0, stream>>>(bufB, aS[l], aD[l], sArr, dArr, N);
        if (l < 2) {
            k_agg<true><<<(N + 3) / 4, 256, 0, stream>>>(bufB, sArr, dArr, rowptr, csr,
                                                         bb[l], bufA, N);
        } else {
            k_agg<false><<<(N + 3) / 4, 256, 0, stream>>>(bufB, sArr, dArr, rowptr, csr,
                                                          bb[l], (float*)d_out, N);
        }
    }
}

// Round 2
// 788.283 us; speedup vs baseline: 1.0789x; 1.0789x over previous
//
#include <hip/hip_runtime.h>
#include <math.h>

#define D 128

// ---------------- CSR build (XCD-partitioned: blockIdx%8 -> dst range) ----------------

__global__ void k_init_deg(int* deg, int N) {
    int i = blockIdx.x * blockDim.x + threadIdx.x;
    if (i < N) deg[i] = 1;   // self-loop pre-counted
}

// partition p = blockIdx%8 handles dst in [p*N/8,(p+1)*N/8); atomics stay XCD-local
__global__ void k_count(const int* __restrict__ ei, int E, int N, int* deg) {
    int part = blockIdx.x & 7;
    int slice = blockIdx.x >> 3;
    int nsl = gridDim.x >> 3;
    int lo = (int)((long long)N * part >> 3);
    int hi = (int)((long long)N * (part + 1) >> 3);
    const int* dst = ei + E;
    for (int i = slice * blockDim.x + threadIdx.x; i < E; i += nsl * blockDim.x) {
        int d = dst[i];
        if (d >= lo && d < hi) atomicAdd(&deg[d], 1);
    }
}

__global__ void k_scan1(const int* __restrict__ deg, int N, int* tmp, int* bsum) {
    __shared__ int sh[256];
    int t = threadIdx.x;
    int i = blockIdx.x * 256 + t;
    int v = (i < N) ? deg[i] : 0;
    sh[t] = v;
    __syncthreads();
    for (int o = 1; o < 256; o <<= 1) {
        int u = (t >= o) ? sh[t - o] : 0;
        __syncthreads();
        sh[t] += u;
        __syncthreads();
    }
    if (i < N) tmp[i] = sh[t] - v;          // exclusive
    if (t == 255) bsum[blockIdx.x] = sh[255];
}

__global__ void k_scan2(int* bsum, int B) {
    __shared__ int sh[256];
    int t = threadIdx.x;
    int v = (t < B) ? bsum[t] : 0;
    sh[t] = v;
    __syncthreads();
    for (int o = 1; o < 256; o <<= 1) {
        int u = (t >= o) ? sh[t - o] : 0;
        __syncthreads();
        sh[t] += u;
        __syncthreads();
    }
    bsum[t] = sh[t] - v;                    // exclusive scan of block sums
}

__global__ void k_scan3(const int* __restrict__ tmp, const int* __restrict__ bscan,
                        int N, int total, int* rowptr, int* fill) {
    int i = blockIdx.x * blockDim.x + threadIdx.x;
    if (i < N) {
        int r = tmp[i] + bscan[i >> 8];
        rowptr[i] = r;
        fill[i] = r;
    }
    if (i == 0) rowptr[N] = total;
}

// partitioned fill: partition p writes only csr slots for its dst range
// (~0.83MB, stays in that XCD's L2 -> evicted once, no partial-line HBM writes)
__global__ void k_fill(const int* __restrict__ ei, int E, int N, int* fill, int* csr) {
    int part = blockIdx.x & 7;
    int slice = blockIdx.x >> 3;
    int nsl = gridDim.x >> 3;
    int lo = (int)((long long)N * part >> 3);
    int hi = (int)((long long)N * (part + 1) >> 3);
    int total = E + N;
    for (int i = slice * blockDim.x + threadIdx.x; i < total; i += nsl * blockDim.x) {
        int s_, d_;
        if (i < E) { s_ = ei[i]; d_ = ei[E + i]; }
        else       { s_ = d_ = i - E; }         // self loop
        if (d_ >= lo && d_ < hi) {
            int p = atomicAdd(&fill[d_], 1);
            csr[p] = s_;
        }
    }
}

// ---------------- expmap0 ----------------

__global__ void k_expmap(const float* __restrict__ x, float* __restrict__ out, int N) {
    int lane = threadIdx.x & 63;
    int node = blockIdx.x * (blockDim.x >> 6) + (threadIdx.x >> 6);
    if (node >= N) return;
    float2 v = *(const float2*)&x[(size_t)node * D + 2 * lane];
    float ss = v.x * v.x + v.y * v.y;
    for (int o = 32; o; o >>= 1) ss += __shfl_xor(ss, o, 64);
    float n = sqrtf(ss);
    n = fmaxf(n, 1e-15f);
    float sc = tanhf(n) / n;
    float2 r;
    r.x = v.x * sc;
    r.y = v.y * sc;
    *(float2*)&out[(size_t)node * D + 2 * lane] = r;
}

// ---------------- fp32 GEMM: H[N,128] = A[N,128] @ W[128,128] ----------------

__global__ __launch_bounds__(256, 2) void k_gemm(const float* __restrict__ A,
                                                 const float* __restrict__ W,
                                                 float* __restrict__ H, int N) {
    __shared__ float Wsh[D * D];
    __shared__ float Ash[32 * D];
    int t = threadIdx.x;
    int row0 = blockIdx.x * 32;
    for (int k = 0; k < D * D; k += 256) Wsh[k + t] = W[k + t];
    for (int k = 0; k < 32 * D; k += 256) {
        int idx = k + t;
        int r = row0 + (idx >> 7);
        Ash[idx] = (r < N) ? A[(size_t)row0 * D + idx] : 0.f;
    }
    __syncthreads();
    int c0 = (t & 31) * 4;
    int r0 = (t >> 5) * 4;
    float acc[4][4] = {};
#pragma unroll 4
    for (int k = 0; k < D; k++) {
        float4 w = *(const float4*)&Wsh[k * D + c0];
        float a0 = Ash[(r0 + 0) * D + k];
        float a1 = Ash[(r0 + 1) * D + k];
        float a2 = Ash[(r0 + 2) * D + k];
        float a3 = Ash[(r0 + 3) * D + k];
        acc[0][0] += a0 * w.x; acc[0][1] += a0 * w.y; acc[0][2] += a0 * w.z; acc[0][3] += a0 * w.w;
        acc[1][0] += a1 * w.x; acc[1][1] += a1 * w.y; acc[1][2] += a1 * w.z; acc[1][3] += a1 * w.w;
        acc[2][0] += a2 * w.x; acc[2][1] += a2 * w.y; acc[2][2] += a2 * w.z; acc[2][3] += a2 * w.w;
        acc[3][0] += a3 * w.x; acc[3][1] += a3 * w.y; acc[3][2] += a3 * w.z; acc[3][3] += a3 * w.w;
    }
    for (int r = 0; r < 4; r++) {
        int gr = row0 + r0 + r;
        if (gr < N) {
            float4 o;
            o.x = acc[r][0]; o.y = acc[r][1]; o.z = acc[r][2]; o.w = acc[r][3];
            *(float4*)&H[(size_t)gr * D + c0] = o;
        }
    }
}

// ---------------- per-node attention dots s = h@a_src, d = h@a_dst ----------------

__global__ void k_sdots(const float* __restrict__ H, const float* __restrict__ aS,
                        const float* __restrict__ aD, float* __restrict__ sA,
                        float* __restrict__ dA, int N) {
    int lane = threadIdx.x & 63;
    int node = blockIdx.x * (blockDim.x >> 6) + (threadIdx.x >> 6);
    if (node >= N) return;
    float2 h2 = *(const float2*)&H[(size_t)node * D + 2 * lane];
    float2 a2 = *(const float2*)&aS[2 * lane];
    float2 b2 = *(const float2*)&aD[2 * lane];
    float vs = h2.x * a2.x + h2.y * a2.y;
    float vd = h2.x * b2.x + h2.y * b2.y;
    for (int o = 32; o; o >>= 1) {
        vs += __shfl_xor(vs, o, 64);
        vd += __shfl_xor(vd, o, 64);
    }
    if (lane == 0) { sA[node] = vs; dA[node] = vd; }
}

// ---------------- single-pass online-softmax aggregation, one wave per dst ----------------

template <bool ACT>
__global__ void k_agg(const float* __restrict__ H, const float* __restrict__ sA,
                      const float* __restrict__ dA, const int* __restrict__ rowptr,
                      const int* __restrict__ csr, const float* __restrict__ bias,
                      float* __restrict__ out, int N) {
    int lane = threadIdx.x & 63;
    int node = blockIdx.x * (blockDim.x >> 6) + (threadIdx.x >> 6);
    if (node >= N) return;
    int start = rowptr[node];
    int end = rowptr[node + 1];
    float di = dA[node];

    float m = -3.4e38f;
    float den = 0.f;
    float acc0 = 0.f, acc1 = 0.f;

    for (int j0 = start; j0 < end; j0 += 64) {
        int j = j0 + lane;
        int sj = 0;
        float e = -3.4e38f;
        if (j < end) {
            sj = csr[j];
            e = sA[sj] + di;
            e = (e > 0.f) ? e : 0.2f * e;
        }
        // chunk max
        float cm = e;
        for (int o = 32; o; o >>= 1) cm = fmaxf(cm, __shfl_xor(cm, o, 64));
        float mnew = fmaxf(m, cm);
        float fac = __expf(m - mnew);                 // first iter: exp(-huge)=0
        float p = (j < end) ? __expf(e - mnew) : 0.f;
        float cd = p;
        for (int o = 32; o; o >>= 1) cd += __shfl_xor(cd, o, 64);
        den = den * fac + cd;
        acc0 *= fac;
        acc1 *= fac;
        m = mnew;

        int cnt = min(64, end - j0);
        for (int tt = 0; tt < cnt; tt++) {
            float wt = __shfl(p, tt, 64);
            int sjt = __shfl(sj, tt, 64);
            float2 hv = *(const float2*)&H[(size_t)sjt * D + 2 * lane];
            acc0 += wt * hv.x;
            acc1 += wt * hv.y;
        }
    }
    float inv = 1.f / den;
    acc0 = acc0 * inv + bias[2 * lane];
    acc1 = acc1 * inv + bias[2 * lane + 1];
    if (ACT) {
        acc0 = 2.f * tanhf(acc0);
        acc1 = 2.f * tanhf(acc1);
    }
    *(float2*)&out[(size_t)node * D + 2 * lane] = make_float2(acc0, acc1);
}

// ---------------- launch ----------------

extern "C" void kernel_launch(void* const* d_in, const int* in_sizes, int n_in,
                              void* d_out, int out_size, void* d_ws, size_t ws_size,
                              hipStream_t stream) {
    const int N = in_sizes[0] / D;
    const int E = in_sizes[1] / 2;
    const float* x = (const float*)d_in[0];
    const int* ei = (const int*)d_in[1];
    const float* Wm[3] = {(const float*)d_in[2], (const float*)d_in[6], (const float*)d_in[10]};
    const float* aS[3] = {(const float*)d_in[3], (const float*)d_in[7], (const float*)d_in[11]};
    const float* aD[3] = {(const float*)d_in[4], (const float*)d_in[8], (const float*)d_in[12]};
    const float* bb[3] = {(const float*)d_in[5], (const float*)d_in[9], (const float*)d_in[13]};

    char* ws = (char*)d_ws;
    size_t off = 0;
    auto alloc = [&](size_t bytes) -> void* {
        void* p = ws + off;
        off = (off + bytes + 511) & ~(size_t)511;
        return p;
    };
    float* bufA = (float*)alloc((size_t)N * D * 4);
    float* bufB = (float*)alloc((size_t)N * D * 4);
    float* sArr = (float*)alloc((size_t)N * 4);
    float* dArr = (float*)alloc((size_t)N * 4);
    int* deg    = (int*)alloc((size_t)N * 4);       // reused as fill cursor
    int* rowptr = (int*)alloc((size_t)(N + 1) * 4);
    int* tmp    = (int*)alloc((size_t)N * 4);
    int* bsum   = (int*)alloc(256 * 4);
    int* csr    = (int*)alloc((size_t)(E + N) * 4);
    (void)ws_size; (void)n_in; (void)out_size;

    const int B1 = (N + 255) / 256;   // 196 for N=50000 (fits single-block scan2)

    k_init_deg<<<B1, 256, 0, stream>>>(deg, N);
    k_count<<<1024, 256, 0, stream>>>(ei, E, N, deg);           // 8 parts x 128 slices
    k_scan1<<<B1, 256, 0, stream>>>(deg, N, tmp, bsum);
    k_scan2<<<1, 256, 0, stream>>>(bsum, B1);
    k_scan3<<<B1, 256, 0, stream>>>(tmp, bsum, N, E + N, rowptr, deg);
    k_fill<<<1024, 256, 0, stream>>>(ei, E, N, deg, csr);       // 8 parts x 128 slices

    k_expmap<<<(N + 3) / 4, 256, 0, stream>>>(x, bufA, N);

    for (int l = 0; l < 3; l++) {
        k_gemm<<<(N + 31) / 32, 256, 0, stream>>>(bufA, Wm[l], bufB, N);
        k_sdots<<<(N + 3) / 4, 256, 0, stream>>>(bufB, aS[l], aD[l], sArr, dArr, N);
        if (l < 2) {
            k_agg<true><<<(N + 3) / 4, 256, 0, stream>>>(bufB, sArr, dArr, rowptr, csr,
                                                         bb[l], bufA, N);
        } else {
            k_agg<false><<<(N + 3) / 4, 256, 0, stream>>>(bufB, sArr, dArr, rowptr, csr,
                                                          bb[l], (float*)d_out, N);
        }
    }
}